// Round 2
// baseline (12935.385 us; speedup 1.0000x reference)
//
#include <hip/hip_runtime.h>
#include <hip/hip_bf16.h>

typedef __hip_bfloat16 bf16;

#define NA    4096
#define NM    16384
#define TCH   2      // t-chunk size (24 = 12 chunks of 2)

__device__ __forceinline__ float b2f(bf16 v) { return __bfloat162float(v); }

__device__ __forceinline__ float ldw(const void* p, size_t i, int bf) {
    if (bf) return b2f(((const bf16*)p)[i]);
    return ((const float*)p)[i];
}

__device__ __forceinline__ bf16 f2b(float f) {
    union { unsigned u; float ff; } cv; cv.ff = f;
    unsigned r = (cv.u + 0x7FFFu + ((cv.u >> 16) & 1u)) >> 16;
    unsigned short us = (unsigned short)r;
    bf16 out; __builtin_memcpy(&out, &us, 2);
    return out;
}

// ---------------- dtype probe: bf16 vs f32 float buffers ----------------
__global__ void k_flag(const void* __restrict__ fnode, int* __restrict__ flag) {
    if (threadIdx.x == 0 && blockIdx.x == 0) {
        const unsigned short* u = (const unsigned short*)fnode;
        int cnt = 0;
        for (int i = 0; i < 64; i++) {
            unsigned short us = u[2 * i];            // low half of f32 OR a real bf16 element
            unsigned ex = (us >> 7) & 0xFF;
            if (us == 0 || (ex >= 105 && ex <= 134)) cnt++;   // |v| in ~[2^-22, 2^7]
        }
        *flag = (cnt >= 48) ? 1 : 0;
    }
}

// ---------------- cast fnode -> f32 ----------------
__global__ void k_cast(const void* __restrict__ in, float* __restrict__ out, int n,
                       const int* __restrict__ flag) {
    int bf = *flag;
    int i = blockIdx.x * 256 + threadIdx.x;
    if (i < n) out[i] = ldw(in, i, bf);
}

// ---------------- GEMM: C[4096 x 256] = A[4096 x K] * W[256 x K]^T (+bias) ----------------
__global__ __launch_bounds__(256) void k_gemm_nt(
    const float* __restrict__ A, const void* __restrict__ W, size_t woff,
    const void* __restrict__ bias, size_t boff, int has_bias,
    float* __restrict__ C, int K, const int* __restrict__ flag)
{
    int bf = *flag;
    __shared__ float Wl[256 * 33];
    __shared__ float Al[32 * 20];
    int a0 = blockIdx.x * 16;
    int c  = threadIdx.x;
    float acc[16];
#pragma unroll
    for (int i = 0; i < 16; i++) acc[i] = 0.f;

    for (int k0 = 0; k0 < K; k0 += 32) {
        __syncthreads();
        for (int i = threadIdx.x; i < 256 * 32; i += 256) {
            int c2 = i >> 5, kk = i & 31, k = k0 + kk;
            Wl[c2 * 33 + kk] = (k < K) ? ldw(W, woff + (size_t)c2 * K + k, bf) : 0.f;
        }
        for (int i = threadIdx.x; i < 512; i += 256) {
            int aa = i >> 5, kk = i & 31, k = k0 + kk;
            Al[kk * 20 + aa] = (k < K) ? A[(size_t)(a0 + aa) * K + k] : 0.f;
        }
        __syncthreads();
#pragma unroll
        for (int kk = 0; kk < 32; kk++) {
            float w = Wl[c * 33 + kk];
            const float4* ap = (const float4*)&Al[kk * 20];
            float4 a01 = ap[0], a23 = ap[1], a45 = ap[2], a67 = ap[3];
            acc[0]  += a01.x * w; acc[1]  += a01.y * w; acc[2]  += a01.z * w; acc[3]  += a01.w * w;
            acc[4]  += a23.x * w; acc[5]  += a23.y * w; acc[6]  += a23.z * w; acc[7]  += a23.w * w;
            acc[8]  += a45.x * w; acc[9]  += a45.y * w; acc[10] += a45.z * w; acc[11] += a45.w * w;
            acc[12] += a67.x * w; acc[13] += a67.y * w; acc[14] += a67.z * w; acc[15] += a67.w * w;
        }
    }
    float bv = has_bias ? ldw(bias, boff + c, bf) : 0.f;
#pragma unroll
    for (int i = 0; i < 16; i++) C[(size_t)(a0 + i) * 256 + c] = acc[i] + bv;
}

// ---------------- transpose x (4096x256) -> xT (256x4096) ----------------
__global__ __launch_bounds__(256) void k_xpose(const float* __restrict__ x, float* __restrict__ xT) {
    __shared__ float tl[32][33];
    int bx = blockIdx.x, by = blockIdx.y;
    int tx = threadIdx.x & 31, ty = threadIdx.x >> 5;
#pragma unroll
    for (int i = 0; i < 4; i++)
        tl[ty + i * 8][tx] = x[(size_t)(bx * 32 + ty + i * 8) * 256 + by * 32 + tx];
    __syncthreads();
#pragma unroll
    for (int i = 0; i < 4; i++)
        xT[(size_t)(by * 32 + ty + i * 8) * NA + bx * 32 + tx] = tl[tx][ty + i * 8];
}

// ---------------- build transposed hmess: hmT[k][m], k<288 (262 valid, zero-padded) ----------------
__global__ void k_hmess(const float* __restrict__ x, const void* __restrict__ fmess,
                        float* __restrict__ hmT, const int* __restrict__ flag) {
    int bf = *flag;
    int idx = blockIdx.x * 256 + threadIdx.x;   // 288*16384 total
    int k = idx >> 14;
    int m = idx & (NM - 1);
    float v = 0.f;
    if (k < 256) {
        int s = (int)ldw(fmess, (size_t)m * 8, bf);
        s = min(max(s, 0), NA - 1);
        v = x[(size_t)s * 256 + k];
    } else if (k < 262) {
        v = ldw(fmess, (size_t)m * 8 + 2 + (k - 256), bf);
    }
    hmT[idx] = v;
}

// ---------------- mol membership map ----------------
__global__ void k_molmap(const int* __restrict__ scopes, int nmol, int* __restrict__ molid) {
    int a = blockIdx.x * 256 + threadIdx.x;
    if (a >= NA) return;
    int mid = -1;
    for (int s2 = 0; s2 < nmol; s2++) {
        int st = scopes[2 * s2], ln = scopes[2 * s2 + 1];
        if (a >= st && a < st + ln) mid = s2;
    }
    molid[a] = mid;
}

// ---------------- precompute r1/az/ah for a chunk of TCH t's ----------------
// grid (NM/512, TCH, 4 dsub); block 256; 2 msgs/lane.  Output layout [(ti*32+d)*NM + m].
__global__ __launch_bounds__(256) void k_pre(
    const float* __restrict__ hmT,
    const void* __restrict__ Wr_w, const void* __restrict__ Wz_w, const void* __restrict__ Wh_w,
    const void* __restrict__ Ur_b, const void* __restrict__ Wz_b, const void* __restrict__ Wh_b,
    int t0, float* __restrict__ r1, float* __restrict__ az, float* __restrict__ ah,
    const int* __restrict__ flag)
{
    int bf = *flag;
    const int ti = blockIdx.y, t = t0 + ti, dsub = blockIdx.z;
    __shared__ float WL[3][8][288];
    for (int i = threadIdx.x; i < 3 * 8 * 288; i += 256) {
        int mt = i / 2304, rr = i - mt * 2304, dj = rr / 288, k = rr - dj * 288;
        int d = dsub * 8 + dj;
        float v = 0.f;
        if (k < 262) {
            if (mt == 0)      v = ldw(Wr_w, ((size_t)t * 32 + d) * 262 + k, bf);
            else if (mt == 1) v = ldw(Wz_w, ((size_t)t * 32 + d) * 294 + k, bf);
            else              v = ldw(Wh_w, ((size_t)t * 32 + d) * 294 + k, bf);
        }
        WL[mt][dj][k] = v;
    }
    __syncthreads();
    int m0 = blockIdx.x * 512 + threadIdx.x;
    int m1 = m0 + 256;
    float aR0[8] = {}, aZ0[8] = {}, aH0[8] = {}, aR1[8] = {}, aZ1[8] = {}, aH1[8] = {};
    for (int kc = 0; kc < 9; kc++) {
        int k0 = kc * 32;
        float hv0[32], hv1[32];
#pragma unroll
        for (int kk = 0; kk < 32; kk++) {
            hv0[kk] = hmT[(size_t)(k0 + kk) * NM + m0];
            hv1[kk] = hmT[(size_t)(k0 + kk) * NM + m1];
        }
#pragma unroll
        for (int dj = 0; dj < 8; dj++) {
#pragma unroll
            for (int kk = 0; kk < 32; kk += 4) {
                float4 wr = *(const float4*)&WL[0][dj][k0 + kk];
                float4 wz = *(const float4*)&WL[1][dj][k0 + kk];
                float4 wh = *(const float4*)&WL[2][dj][k0 + kk];
                aR0[dj] += hv0[kk] * wr.x + hv0[kk + 1] * wr.y + hv0[kk + 2] * wr.z + hv0[kk + 3] * wr.w;
                aR1[dj] += hv1[kk] * wr.x + hv1[kk + 1] * wr.y + hv1[kk + 2] * wr.z + hv1[kk + 3] * wr.w;
                aZ0[dj] += hv0[kk] * wz.x + hv0[kk + 1] * wz.y + hv0[kk + 2] * wz.z + hv0[kk + 3] * wz.w;
                aZ1[dj] += hv1[kk] * wz.x + hv1[kk + 1] * wz.y + hv1[kk + 2] * wz.z + hv1[kk + 3] * wz.w;
                aH0[dj] += hv0[kk] * wh.x + hv0[kk + 1] * wh.y + hv0[kk + 2] * wh.z + hv0[kk + 3] * wh.w;
                aH1[dj] += hv1[kk] * wh.x + hv1[kk + 1] * wh.y + hv1[kk + 2] * wh.z + hv1[kk + 3] * wh.w;
            }
        }
    }
#pragma unroll
    for (int dj = 0; dj < 8; dj++) {
        int d = dsub * 8 + dj;
        size_t row = (size_t)(ti * 32 + d) * NM;
        float rb  = ldw(Ur_b, t * 32 + d, bf);
        float zb  = ldw(Wz_b, t * 32 + d, bf);
        float hb2 = ldw(Wh_b, t * 32 + d, bf);
        r1[row + m0] = aR0[dj] + rb;  r1[row + m1] = aR1[dj] + rb;
        az[row + m0] = aZ0[dj] + zb;  az[row + m1] = aZ1[dj] + zb;
        ah[row + m0] = aH0[dj] + hb2; ah[row + m1] = aH1[dj] + hb2;
    }
}

// ---------------- one GRU depth step for a chunk ----------------
// grid (NM/256, TCH); block 256; lane = message; h layout [(ti*NM+m)*32+d]
__global__ __launch_bounds__(256) void k_step(
    const float* __restrict__ h_in, float* __restrict__ h_out,
    const float* __restrict__ r1, const float* __restrict__ az, const float* __restrict__ ah,
    const int* __restrict__ bgraph,
    const void* __restrict__ Ur_w, const void* __restrict__ Wz_w, const void* __restrict__ Wh_w,
    int t0, const int* __restrict__ flag)
{
    int bf = *flag;
    const int ti = blockIdx.y, t = t0 + ti;
    __shared__ float UrL[32 * 36], WzL[32 * 36], WhL[32 * 36];
    for (int i = threadIdx.x; i < 32 * 36; i += 256) {
        int d = i / 36, j = i - d * 36;
        float u = 0.f, wz = 0.f, wh = 0.f;
        if (j < 32) {
            u  = ldw(Ur_w, ((size_t)t * 32 + d) * 32 + j, bf);
            wz = ldw(Wz_w, ((size_t)t * 32 + d) * 294 + 262 + j, bf);
            wh = ldw(Wh_w, ((size_t)t * 32 + d) * 294 + 262 + j, bf);
        }
        UrL[i] = u; WzL[i] = wz; WhL[i] = wh;
    }
    __syncthreads();
    int m = blockIdx.x * 256 + threadIdx.x;
    const float* hb = h_in + (size_t)ti * NM * 32;
    float r1v[32];
#pragma unroll
    for (int d = 0; d < 32; d++) r1v[d] = r1[(size_t)(ti * 32 + d) * NM + m];
    float sumh[32], rh[32];
#pragma unroll
    for (int d = 0; d < 32; d++) { sumh[d] = 0.f; rh[d] = 0.f; }
#pragma unroll
    for (int nb = 0; nb < 6; nb++) {
        int bg = bgraph[m * 6 + nb];
        bg = min(max(bg, 0), NM - 1);
        const float* hr = hb + (size_t)bg * 32;
        float hc[32];
#pragma unroll
        for (int j4 = 0; j4 < 32; j4 += 4) {
            float4 v = *(const float4*)&hr[j4];
            hc[j4] = v.x; hc[j4 + 1] = v.y; hc[j4 + 2] = v.z; hc[j4 + 3] = v.w;
        }
#pragma unroll
        for (int d = 0; d < 32; d++) sumh[d] += hc[d];
#pragma unroll
        for (int d = 0; d < 32; d++) {
            float acc = r1v[d];
#pragma unroll
            for (int j = 0; j < 32; j++) acc += hc[j] * UrL[d * 36 + j];
            float rr = 1.f / (1.f + __expf(-acc));
            rh[d] += rr * hc[d];
        }
    }
    float msk = (m == 0) ? 0.f : 1.f;
    float* ho = h_out + ((size_t)ti * NM + m) * 32;
#pragma unroll
    for (int d = 0; d < 32; d++) {
        float zacc = az[(size_t)(ti * 32 + d) * NM + m];
        float pacc = ah[(size_t)(ti * 32 + d) * NM + m];
#pragma unroll
        for (int j = 0; j < 32; j++) {
            zacc += sumh[j] * WzL[d * 36 + j];
            pacc += rh[j]   * WhL[d * 36 + j];
        }
        float zz = 1.f / (1.f + __expf(-zacc));
        float cl = fminf(fmaxf(pacc, -20.f), 20.f);
        float e2 = __expf(2.f * cl);
        float th = (e2 - 1.f) / (e2 + 1.f);
        ho[d] = ((1.f - zz) * sumh[d] + zz * th) * msk;
    }
}

// ---------------- outs = relu([x, nei] @ Wo^T + b) * node_mask, scattered into qkv ----------------
// grid (NA/256, TCH, 4 dsub); block 256; lane = atom.
__global__ __launch_bounds__(256) void k_outs(
    const float* __restrict__ xT, const float* __restrict__ h,
    const int* __restrict__ agraph, const void* __restrict__ Wo_w, const void* __restrict__ Wo_b,
    int t0, float* __restrict__ qkv, const int* __restrict__ flag)
{
    int bf = *flag;
    const int ti = blockIdx.y, t = t0 + ti, dsub = blockIdx.z;
    const int hh = t / 3, s2 = t - 3 * hh;
    __shared__ float WL[8 * 296];
    for (int i = threadIdx.x; i < 8 * 296; i += 256) {
        int dj = i / 296, k = i - dj * 296;
        int d = dsub * 8 + dj;
        WL[i] = (k < 288) ? ldw(Wo_w, ((size_t)t * 32 + d) * 288 + k, bf) : 0.f;
    }
    __syncthreads();
    int a = blockIdx.x * 256 + threadIdx.x;
    float nei[32];
#pragma unroll
    for (int j = 0; j < 32; j++) nei[j] = 0.f;
#pragma unroll
    for (int nb = 0; nb < 6; nb++) {
        int ag = agraph[a * 6 + nb];
        ag = min(max(ag, 0), NM - 1);
        const float* hr = h + ((size_t)ti * NM + ag) * 32;
#pragma unroll
        for (int j4 = 0; j4 < 32; j4 += 4) {
            float4 v = *(const float4*)&hr[j4];
            nei[j4] += v.x; nei[j4 + 1] += v.y; nei[j4 + 2] += v.z; nei[j4 + 3] += v.w;
        }
    }
    float acc[8];
#pragma unroll
    for (int dj = 0; dj < 8; dj++) acc[dj] = ldw(Wo_b, t * 32 + dsub * 8 + dj, bf);
    for (int kc = 0; kc < 8; kc++) {
        float xv[32];
#pragma unroll
        for (int kk = 0; kk < 32; kk++) xv[kk] = xT[(size_t)(kc * 32 + kk) * NA + a];
#pragma unroll
        for (int dj = 0; dj < 8; dj++) {
#pragma unroll
            for (int kk = 0; kk < 32; kk += 4) {
                float4 w = *(const float4*)&WL[dj * 296 + kc * 32 + kk];
                acc[dj] += xv[kk] * w.x + xv[kk + 1] * w.y + xv[kk + 2] * w.z + xv[kk + 3] * w.w;
            }
        }
    }
#pragma unroll
    for (int dj = 0; dj < 8; dj++) {
#pragma unroll
        for (int j = 0; j < 32; j += 4) {
            float4 w = *(const float4*)&WL[dj * 296 + 256 + j];
            acc[dj] += nei[j] * w.x + nei[j + 1] * w.y + nei[j + 2] * w.z + nei[j + 3] * w.w;
        }
        float o = fmaxf(acc[dj], 0.f);
        if (a == 0) o = 0.f;
        int d = dsub * 8 + dj;
        size_t dst;
        if (s2 == 0) dst = (size_t)a * 256 + hh * 32 + d;                                 // queries[a, hh*32+d]
        else dst = (size_t)s2 * 1048576 + (size_t)hh * 131072 + (size_t)a * 32 + d;       // keys/values scrambled
        qkv[dst] = o;
    }
}

// ---------------- per-molecule 32x32 attention block ----------------
// grid (nmol, 4); block 64 (one wave, 2 heads)
__global__ __launch_bounds__(64) void k_attn_mol(
    const float* __restrict__ Qp, const float* __restrict__ Kp, const float* __restrict__ Vp,
    const int* __restrict__ scopes, float* __restrict__ ctx)
{
    int mol = blockIdx.x;
    int g = threadIdx.x >> 5;
    int head = blockIdx.y * 2 + g;
    int lane = threadIdx.x & 31;
    int start = scopes[2 * mol];
    int len = min(scopes[2 * mol + 1], 32);
    if (len <= 0) return;
    __shared__ float Ql[2][32 * 36], Kl[2][32 * 36], Vl[2][32 * 36], Pl[2][32 * 36];
    for (int i = 0; i < len; i++) {
        if (start + i >= NA) break;
        size_t base = (size_t)(start + i) * 256 + head * 32 + lane;
        Ql[g][i * 36 + lane] = Qp[base];
        Kl[g][i * 36 + lane] = Kp[base];
        Vl[g][i * 36 + lane] = Vp[base];
    }
    for (int i = len; i < 32; i++) { Vl[g][i * 36 + lane] = 0.f; Kl[g][i * 36 + lane] = 0.f; }
    float kreg[32];
#pragma unroll
    for (int d2 = 0; d2 < 32; d2++) kreg[d2] = Kl[g][lane * 36 + d2];
    const float scale = 0.17677669529663687f;   // 1/sqrt(32)
    for (int i = 0; i < len; i++) {
        float s = 0.f;
#pragma unroll
        for (int d2 = 0; d2 < 32; d2++) s += Ql[g][i * 36 + d2] * kreg[d2];
        s *= scale;
        if (lane >= len) s = -1e30f;
        float mx = s;
#pragma unroll
        for (int off = 16; off > 0; off >>= 1) mx = fmaxf(mx, __shfl_xor(mx, off, 32));
        float p = __expf(s - mx);
        if (lane >= len) p = 0.f;
        float sum = p;
#pragma unroll
        for (int off = 16; off > 0; off >>= 1) sum += __shfl_xor(sum, off, 32);
        Pl[g][i * 36 + lane] = p / sum;
    }
    for (int i = 0; i < len; i++) {
        if (start + i >= NA) break;
        float acc = 0.f;
#pragma unroll
        for (int j = 0; j < 32; j++) acc += Pl[g][i * 36 + j] * Vl[g][j * 36 + lane];
        ctx[(size_t)(start + i) * 256 + head * 32 + lane] = acc;
    }
}

// ---------------- degenerate attention rows: atom 0 -> V[0]; uncovered atoms -> mean(V) ----------------
__global__ __launch_bounds__(256) void k_attn_uniform(
    const float* __restrict__ Vp, const int* __restrict__ molid, float* __restrict__ ctx)
{
    int head = blockIdx.x;
    int s = threadIdx.x >> 5, d = threadIdx.x & 31;
    float part = 0.f;
    for (int a = s; a < NA; a += 8) part += Vp[(size_t)a * 256 + head * 32 + d];
    __shared__ float red[8 * 33];
    __shared__ float mv[32];
    red[s * 33 + d] = part;
    __syncthreads();
    if (threadIdx.x < 32) {
        float tot = 0.f;
#pragma unroll
        for (int ss = 0; ss < 8; ss++) tot += red[ss * 33 + threadIdx.x];
        mv[threadIdx.x] = tot * (1.f / 4096.f);
    }
    __syncthreads();
    float meanv = mv[d];
    float v0 = Vp[head * 32 + d];
    for (int a = s; a < NA; a += 8) {
        if (molid[a] < 0) ctx[(size_t)a * 256 + head * 32 + d] = (a == 0) ? v0 : meanv;
    }
}

// ---------------- layernorm -> out (bf16 or f32 per flag) ----------------
__global__ __launch_bounds__(256) void k_ln(
    const float* __restrict__ xo, const void* __restrict__ g_, const void* __restrict__ b_,
    void* __restrict__ out, const int* __restrict__ flag)
{
    int bf = *flag;
    int a = blockIdx.x, c = threadIdx.x;
    float v = xo[(size_t)a * 256 + c];
    __shared__ float red[4], red2[4];
    float s = v;
#pragma unroll
    for (int off = 32; off > 0; off >>= 1) s += __shfl_down(s, off);
    int w = threadIdx.x >> 6, ln2 = threadIdx.x & 63;
    if (ln2 == 0) red[w] = s;
    __syncthreads();
    float mu = (red[0] + red[1] + red[2] + red[3]) * (1.f / 256.f);
    float dv = v - mu;
    float sq = dv * dv;
#pragma unroll
    for (int off = 32; off > 0; off >>= 1) sq += __shfl_down(sq, off);
    if (ln2 == 0) red2[w] = sq;
    __syncthreads();
    float var = (red2[0] + red2[1] + red2[2] + red2[3]) * (1.f / 256.f);
    float y = dv * rsqrtf(var + 1e-5f) * ldw(g_, c, bf) + ldw(b_, c, bf);
    size_t idx = (size_t)a * 256 + c;
    if (bf) ((bf16*)out)[idx] = f2b(y);
    else    ((float*)out)[idx] = y;
}

extern "C" void kernel_launch(void* const* d_in, const int* in_sizes, int n_in,
                              void* d_out, int out_size, void* d_ws, size_t ws_size,
                              hipStream_t stream)
{
    const void* fnode  = d_in[0];
    const void* fmess  = d_in[1];
    const int*  agraph = (const int*)d_in[2];
    const int*  bgraph = (const int*)d_in[3];
    const int*  scopes = (const int*)d_in[4];
    const void* W_i_w  = d_in[5];
    const void* Wz_w   = d_in[6];
    const void* Wz_b   = d_in[7];
    const void* Wr_w   = d_in[8];
    const void* Ur_w   = d_in[9];
    const void* Ur_b   = d_in[10];
    const void* Wh_w   = d_in[11];
    const void* Wh_b   = d_in[12];
    const void* Wo_w   = d_in[13];
    const void* Wo_b   = d_in[14];
    const void* attn_w = d_in[15];
    const void* attn_b = d_in[16];
    const void* aow    = d_in[17];
    const void* bww    = d_in[18];
    const void* ln_g   = d_in[19];
    const void* ln_b   = d_in[20];
    int nmol = in_sizes[4] / 2;

    // -------- workspace layout (floats), ~56.6 MB --------
    const size_t CS = (size_t)TCH * 32 * NM;     // 1,048,576 per state array (TCH=2)
    float* p   = (float*)d_ws;
    float* xT  = p;                    p += 1048576;
    float* hmT = p;                    p += (size_t)288 * NM;       // 4,718,592
    float* cs  = p;                    p += 5 * CS;                 // 5,242,880
    float* qkv = p;                    p += 3 * 1048576;            // 3,145,728
    int*   molid = (int*)p;            p += NA;
    int*   dflag = (int*)p;            p += 1;

    float* r1 = cs;
    float* az = cs + CS;
    float* ah = cs + 2 * CS;
    float* h0 = cs + 3 * CS;
    float* h1 = cs + 4 * CS;
    // phase-A temporaries nested inside qkv (dead before qkv is written):
    float* fnode_f = qkv;              // 401,408
    float* x       = qkv + 524288;     // 1,048,576
    // post-loop aliases:
    float* Qp  = cs;                   // 1,048,576 each
    float* Kp  = cs + 1048576;
    float* Vp  = cs + 2097152;
    float* ctx = hmT;
    float* y1  = hmT + 1048576;
    float* xo  = hmT + 2097152;

    k_flag<<<1, 64, 0, stream>>>(fnode, dflag);
    k_cast<<<(401408 + 255) / 256, 256, 0, stream>>>(fnode, fnode_f, 401408, dflag);
    k_gemm_nt<<<256, 256, 0, stream>>>(fnode_f, W_i_w, 0, nullptr, 0, 0, x, 98, dflag);
    k_xpose<<<dim3(128, 8), 256, 0, stream>>>(x, xT);
    k_hmess<<<(288 * NM) / 256, 256, 0, stream>>>(x, fmess, hmT, dflag);
    k_molmap<<<(NA + 255) / 256, 256, 0, stream>>>(scopes, nmol, molid);

    for (int tc = 0; tc < 24 / TCH; tc++) {
        int t0 = tc * TCH;
        k_pre<<<dim3(NM / 512, TCH, 4), 256, 0, stream>>>(
            hmT, Wr_w, Wz_w, Wh_w, Ur_b, Wz_b, Wh_b, t0, r1, az, ah, dflag);
        hipMemsetAsync(h0, 0, CS * sizeof(float), stream);
        k_step<<<dim3(NM / 256, TCH), 256, 0, stream>>>(h0, h1, r1, az, ah, bgraph, Ur_w, Wz_w, Wh_w, t0, dflag);
        k_step<<<dim3(NM / 256, TCH), 256, 0, stream>>>(h1, h0, r1, az, ah, bgraph, Ur_w, Wz_w, Wh_w, t0, dflag);
        k_step<<<dim3(NM / 256, TCH), 256, 0, stream>>>(h0, h1, r1, az, ah, bgraph, Ur_w, Wz_w, Wh_w, t0, dflag);
        k_outs<<<dim3(NA / 256, TCH, 4), 256, 0, stream>>>(xT, h1, agraph, Wo_w, Wo_b, t0, qkv, dflag);
    }

    // projections (qkv planes already in queries/keys/values layout); offsets in ELEMENTS
    k_gemm_nt<<<256, 256, 0, stream>>>(qkv,           attn_w, 0,      attn_b, 0,   1, Qp, 256, dflag);
    k_gemm_nt<<<256, 256, 0, stream>>>(qkv + 1048576, attn_w, 65536,  attn_b, 256, 1, Kp, 256, dflag);
    k_gemm_nt<<<256, 256, 0, stream>>>(qkv + 2097152, attn_w, 131072, attn_b, 512, 1, Vp, 256, dflag);

    k_attn_mol<<<dim3(nmol, 4), 64, 0, stream>>>(Qp, Kp, Vp, scopes, ctx);
    k_attn_uniform<<<8, 256, 0, stream>>>(Vp, molid, ctx);

    k_gemm_nt<<<256, 256, 0, stream>>>(ctx, aow, 0, nullptr, 0, 0, y1, 256, dflag);
    k_gemm_nt<<<256, 256, 0, stream>>>(y1,  bww, 0, nullptr, 0, 0, xo, 256, dflag);
    k_ln<<<NA, 256, 0, stream>>>(xo, ln_g, ln_b, d_out, dflag);
    (void)ws_size; (void)out_size; (void)n_in;
}

// Round 3
// 3333.231 us; speedup vs baseline: 3.8807x; 3.8807x over previous
//
#include <hip/hip_runtime.h>
#include <hip/hip_bf16.h>

typedef __hip_bfloat16 bf16;

#define NA    4096
#define NM    16384
#define TCH   2      // t-chunk size (24 = 12 chunks of 2)

__device__ __forceinline__ float b2f(bf16 v) { return __bfloat162float(v); }

__device__ __forceinline__ float ldw(const void* p, size_t i, int bf) {
    if (bf) return b2f(((const bf16*)p)[i]);
    return ((const float*)p)[i];
}

__device__ __forceinline__ bf16 f2b(float f) {
    union { unsigned u; float ff; } cv; cv.ff = f;
    unsigned r = (cv.u + 0x7FFFu + ((cv.u >> 16) & 1u)) >> 16;
    unsigned short us = (unsigned short)r;
    bf16 out; __builtin_memcpy(&out, &us, 2);
    return out;
}

// ---------------- dtype probe: bf16 vs f32 float buffers ----------------
__global__ void k_flag(const void* __restrict__ fnode, int* __restrict__ flag) {
    if (threadIdx.x == 0 && blockIdx.x == 0) {
        const unsigned short* u = (const unsigned short*)fnode;
        int cnt = 0;
        for (int i = 0; i < 64; i++) {
            unsigned short us = u[2 * i];
            unsigned ex = (us >> 7) & 0xFF;
            if (us == 0 || (ex >= 105 && ex <= 134)) cnt++;
        }
        *flag = (cnt >= 48) ? 1 : 0;
    }
}

// ---------------- cast fnode -> f32 ----------------
__global__ void k_cast(const void* __restrict__ in, float* __restrict__ out, int n,
                       const int* __restrict__ flag) {
    int bf = *flag;
    int i = blockIdx.x * 256 + threadIdx.x;
    if (i < n) out[i] = ldw(in, i, bf);
}

// ---------------- GEMM: C[4096 x 256] = A[4096 x K] * W[256 x K]^T (+bias) ----------------
__global__ __launch_bounds__(256) void k_gemm_nt(
    const float* __restrict__ A, const void* __restrict__ W, size_t woff,
    const void* __restrict__ bias, size_t boff, int has_bias,
    float* __restrict__ C, int K, const int* __restrict__ flag)
{
    int bf = *flag;
    __shared__ float Wl[256 * 33];
    __shared__ float Al[32 * 20];
    int a0 = blockIdx.x * 16;
    int c  = threadIdx.x;
    float acc[16];
#pragma unroll
    for (int i = 0; i < 16; i++) acc[i] = 0.f;

    for (int k0 = 0; k0 < K; k0 += 32) {
        __syncthreads();
        for (int i = threadIdx.x; i < 256 * 32; i += 256) {
            int c2 = i >> 5, kk = i & 31, k = k0 + kk;
            Wl[c2 * 33 + kk] = (k < K) ? ldw(W, woff + (size_t)c2 * K + k, bf) : 0.f;
        }
        for (int i = threadIdx.x; i < 512; i += 256) {
            int aa = i >> 5, kk = i & 31, k = k0 + kk;
            Al[kk * 20 + aa] = (k < K) ? A[(size_t)(a0 + aa) * K + k] : 0.f;
        }
        __syncthreads();
#pragma unroll
        for (int kk = 0; kk < 32; kk++) {
            float w = Wl[c * 33 + kk];
            const float4* ap = (const float4*)&Al[kk * 20];
            float4 a01 = ap[0], a23 = ap[1], a45 = ap[2], a67 = ap[3];
            acc[0]  += a01.x * w; acc[1]  += a01.y * w; acc[2]  += a01.z * w; acc[3]  += a01.w * w;
            acc[4]  += a23.x * w; acc[5]  += a23.y * w; acc[6]  += a23.z * w; acc[7]  += a23.w * w;
            acc[8]  += a45.x * w; acc[9]  += a45.y * w; acc[10] += a45.z * w; acc[11] += a45.w * w;
            acc[12] += a67.x * w; acc[13] += a67.y * w; acc[14] += a67.z * w; acc[15] += a67.w * w;
        }
    }
    float bv = has_bias ? ldw(bias, boff + c, bf) : 0.f;
#pragma unroll
    for (int i = 0; i < 16; i++) C[(size_t)(a0 + i) * 256 + c] = acc[i] + bv;
}

// ---------------- transpose x (4096x256) -> xT (256x4096) ----------------
__global__ __launch_bounds__(256) void k_xpose(const float* __restrict__ x, float* __restrict__ xT) {
    __shared__ float tl[32][33];
    int bx = blockIdx.x, by = blockIdx.y;
    int tx = threadIdx.x & 31, ty = threadIdx.x >> 5;
#pragma unroll
    for (int i = 0; i < 4; i++)
        tl[ty + i * 8][tx] = x[(size_t)(bx * 32 + ty + i * 8) * 256 + by * 32 + tx];
    __syncthreads();
#pragma unroll
    for (int i = 0; i < 4; i++)
        xT[(size_t)(by * 32 + ty + i * 8) * NA + bx * 32 + tx] = tl[tx][ty + i * 8];
}

// ---------------- build transposed hmess: hmT[k][m], k<288 (262 valid, zero-padded) ----------------
__global__ void k_hmess(const float* __restrict__ x, const void* __restrict__ fmess,
                        float* __restrict__ hmT, const int* __restrict__ flag) {
    int bf = *flag;
    int idx = blockIdx.x * 256 + threadIdx.x;   // 288*16384 total
    int k = idx >> 14;
    int m = idx & (NM - 1);
    float v = 0.f;
    if (k < 256) {
        int s = (int)ldw(fmess, (size_t)m * 8, bf);
        s = min(max(s, 0), NA - 1);
        v = x[(size_t)s * 256 + k];
    } else if (k < 262) {
        v = ldw(fmess, (size_t)m * 8 + 2 + (k - 256), bf);
    }
    hmT[idx] = v;
}

// ---------------- mol membership map ----------------
__global__ void k_molmap(const int* __restrict__ scopes, int nmol, int* __restrict__ molid) {
    int a = blockIdx.x * 256 + threadIdx.x;
    if (a >= NA) return;
    int mid = -1;
    for (int s2 = 0; s2 < nmol; s2++) {
        int st = scopes[2 * s2], ln = scopes[2 * s2 + 1];
        if (a >= st && a < st + ln) mid = s2;
    }
    molid[a] = mid;
}

// ---------------- precompute r1/az/ah for a chunk of TCH t's ----------------
// grid (NM/512, TCH, 4 dsub); block 256; 2 msgs/lane.  Output layout [(ti*32+d)*NM + m].
__global__ __launch_bounds__(256) void k_pre(
    const float* __restrict__ hmT,
    const void* __restrict__ Wr_w, const void* __restrict__ Wz_w, const void* __restrict__ Wh_w,
    const void* __restrict__ Ur_b, const void* __restrict__ Wz_b, const void* __restrict__ Wh_b,
    int t0, float* __restrict__ r1, float* __restrict__ az, float* __restrict__ ah,
    const int* __restrict__ flag)
{
    int bf = *flag;
    const int ti = blockIdx.y, t = t0 + ti, dsub = blockIdx.z;
    __shared__ float WL[3][8][288];
    for (int i = threadIdx.x; i < 3 * 8 * 288; i += 256) {
        int mt = i / 2304, rr = i - mt * 2304, dj = rr / 288, k = rr - dj * 288;
        int d = dsub * 8 + dj;
        float v = 0.f;
        if (k < 262) {
            if (mt == 0)      v = ldw(Wr_w, ((size_t)t * 32 + d) * 262 + k, bf);
            else if (mt == 1) v = ldw(Wz_w, ((size_t)t * 32 + d) * 294 + k, bf);
            else              v = ldw(Wh_w, ((size_t)t * 32 + d) * 294 + k, bf);
        }
        WL[mt][dj][k] = v;
    }
    __syncthreads();
    int m0 = blockIdx.x * 512 + threadIdx.x;
    int m1 = m0 + 256;
    float aR0[8] = {}, aZ0[8] = {}, aH0[8] = {}, aR1[8] = {}, aZ1[8] = {}, aH1[8] = {};
    for (int kc = 0; kc < 9; kc++) {
        int k0 = kc * 32;
        float hv0[32], hv1[32];
#pragma unroll
        for (int kk = 0; kk < 32; kk++) {
            hv0[kk] = hmT[(size_t)(k0 + kk) * NM + m0];
            hv1[kk] = hmT[(size_t)(k0 + kk) * NM + m1];
        }
#pragma unroll
        for (int dj = 0; dj < 8; dj++) {
#pragma unroll
            for (int kk = 0; kk < 32; kk += 4) {
                float4 wr = *(const float4*)&WL[0][dj][k0 + kk];
                float4 wz = *(const float4*)&WL[1][dj][k0 + kk];
                float4 wh = *(const float4*)&WL[2][dj][k0 + kk];
                aR0[dj] += hv0[kk] * wr.x + hv0[kk + 1] * wr.y + hv0[kk + 2] * wr.z + hv0[kk + 3] * wr.w;
                aR1[dj] += hv1[kk] * wr.x + hv1[kk + 1] * wr.y + hv1[kk + 2] * wr.z + hv1[kk + 3] * wr.w;
                aZ0[dj] += hv0[kk] * wz.x + hv0[kk + 1] * wz.y + hv0[kk + 2] * wz.z + hv0[kk + 3] * wz.w;
                aZ1[dj] += hv1[kk] * wz.x + hv1[kk + 1] * wz.y + hv1[kk + 2] * wz.z + hv1[kk + 3] * wz.w;
                aH0[dj] += hv0[kk] * wh.x + hv0[kk + 1] * wh.y + hv0[kk + 2] * wh.z + hv0[kk + 3] * wh.w;
                aH1[dj] += hv1[kk] * wh.x + hv1[kk + 1] * wh.y + hv1[kk + 2] * wh.z + hv1[kk + 3] * wh.w;
            }
        }
    }
#pragma unroll
    for (int dj = 0; dj < 8; dj++) {
        int d = dsub * 8 + dj;
        size_t row = (size_t)(ti * 32 + d) * NM;
        float rb  = ldw(Ur_b, t * 32 + d, bf);
        float zb  = ldw(Wz_b, t * 32 + d, bf);
        float hb2 = ldw(Wh_b, t * 32 + d, bf);
        r1[row + m0] = aR0[dj] + rb;  r1[row + m1] = aR1[dj] + rb;
        az[row + m0] = aZ0[dj] + zb;  az[row + m1] = aZ1[dj] + zb;
        ah[row + m0] = aH0[dj] + hb2; ah[row + m1] = aH1[dj] + hb2;
    }
}

// ---------------- depth-1 GRU step (h_in == 0): h = sigmoid(az)*tanh(ah)*mask ----------------
// grid (NM/64, TCH); block 256 = 64 messages x 4 d-quarters
__global__ __launch_bounds__(256) void k_step0(
    const float* __restrict__ az, const float* __restrict__ ah, float* __restrict__ h_out)
{
    const int ti = blockIdx.y;
    __shared__ float tb[4][16 * 33];
    const int q = threadIdx.x & 3, ml = threadIdx.x >> 2;
    const int m = blockIdx.x * 64 + ml;
    const int d0 = q * 8;
    const int wv = threadIdx.x >> 6, l = threadIdx.x & 63, mw = ml & 15;
    float msk_m = (m == 0) ? 0.f : 1.f;
#pragma unroll
    for (int dd = 0; dd < 8; dd++) {
        int d = d0 + dd;
        float zacc = az[(size_t)(ti * 32 + d) * NM + m];
        float pacc = ah[(size_t)(ti * 32 + d) * NM + m];
        float zz = 1.f / (1.f + __expf(-zacc));
        float cl = fminf(fmaxf(pacc, -20.f), 20.f);
        float e2 = __expf(2.f * cl);
        float th = (e2 - 1.f) / (e2 + 1.f);
        tb[wv][mw * 33 + d] = zz * th * msk_m;
    }
    __syncthreads();
    float* ho = h_out + (size_t)ti * NM * 32 + ((size_t)blockIdx.x * 64 + wv * 16) * 32;
#pragma unroll
    for (int i = 0; i < 8; i++) {
        int idx = i * 64 + l;
        int mm = idx >> 5, d = idx & 31;
        ho[idx] = tb[wv][mm * 33 + d];
    }
}

// ---------------- full GRU depth step ----------------
// grid (NM/64, TCH); block 256 = 64 messages x 4 d-quarters; h layout [(ti*NM+m)*32+d]
__global__ __launch_bounds__(256, 4) void k_step(
    const float* __restrict__ h_in, float* __restrict__ h_out,
    const float* __restrict__ r1, const float* __restrict__ az, const float* __restrict__ ah,
    const int* __restrict__ bgraph,
    const void* __restrict__ Ur_w, const void* __restrict__ Wz_w, const void* __restrict__ Wh_w,
    int t0, const int* __restrict__ flag)
{
    int bf = *flag;
    const int ti = blockIdx.y, t = t0 + ti;
    __shared__ float UrL[32 * 37], WzL[32 * 37], WhL[32 * 37];   // pad 37: q-groups on distinct banks
    __shared__ float tb[4][16 * 33];
    for (int i = threadIdx.x; i < 32 * 37; i += 256) {
        int d = i / 37, j = i - d * 37;
        float u = 0.f, wz = 0.f, wh = 0.f;
        if (j < 32) {
            u  = ldw(Ur_w, ((size_t)t * 32 + d) * 32 + j, bf);
            wz = ldw(Wz_w, ((size_t)t * 32 + d) * 294 + 262 + j, bf);
            wh = ldw(Wh_w, ((size_t)t * 32 + d) * 294 + 262 + j, bf);
        }
        UrL[i] = u; WzL[i] = wz; WhL[i] = wh;
    }
    __syncthreads();
    const int q  = threadIdx.x & 3;         // d-quarter (4 lanes per message, adjacent)
    const int ml = threadIdx.x >> 2;        // message within block
    const int m  = blockIdx.x * 64 + ml;
    const int d0 = q * 8;
    const float* hb = h_in + (size_t)ti * NM * 32;

    float r1v[8];
#pragma unroll
    for (int dd = 0; dd < 8; dd++)
        r1v[dd] = r1[(size_t)(ti * 32 + d0 + dd) * NM + m];

    float sumh[8], rh[8];
#pragma unroll
    for (int dd = 0; dd < 8; dd++) { sumh[dd] = 0.f; rh[dd] = 0.f; }

#pragma unroll
    for (int nb = 0; nb < 6; nb++) {
        int bg = bgraph[m * 6 + nb];
        bg = min(max(bg, 0), NM - 1);
        const float* hr = hb + (size_t)bg * 32;
        float hc[32];
#pragma unroll
        for (int j4 = 0; j4 < 32; j4 += 4) {
            float4 v = *(const float4*)&hr[j4];
            hc[j4] = v.x; hc[j4 + 1] = v.y; hc[j4 + 2] = v.z; hc[j4 + 3] = v.w;
        }
        float4 o1 = *(const float4*)&hr[d0];        // own quarter (runtime offset -> global, not reg-indexed)
        float4 o2 = *(const float4*)&hr[d0 + 4];
        float hown[8] = {o1.x, o1.y, o1.z, o1.w, o2.x, o2.y, o2.z, o2.w};
#pragma unroll
        for (int dd = 0; dd < 8; dd++) {
            float acc = r1v[dd];
            const float* ur = &UrL[(d0 + dd) * 37];
#pragma unroll
            for (int j = 0; j < 32; j++) acc += hc[j] * ur[j];
            float rr = 1.f / (1.f + __expf(-acc));
            sumh[dd] += hown[dd];
            rh[dd] += rr * hown[dd];
        }
    }
    // quarter exchange within each message's 4 lanes
    float recvS[4][8], recvH[4][8];
#pragma unroll
    for (int e = 0; e < 4; e++)
#pragma unroll
        for (int jj = 0; jj < 8; jj++) {
            recvS[e][jj] = __shfl_xor(sumh[jj], e, 4);
            recvH[e][jj] = __shfl_xor(rh[jj], e, 4);
        }
    float msk_m = (m == 0) ? 0.f : 1.f;
    const int wv = threadIdx.x >> 6, l = threadIdx.x & 63, mw = ml & 15;
#pragma unroll
    for (int dd = 0; dd < 8; dd++) {
        int d = d0 + dd;
        float zacc = az[(size_t)(ti * 32 + d) * NM + m];
        float pacc = ah[(size_t)(ti * 32 + d) * NM + m];
#pragma unroll
        for (int e = 0; e < 4; e++) {
            int jb = (q ^ e) * 8;                    // runtime -> LDS index only
            const float* wz = &WzL[d * 37 + jb];
            const float* wh = &WhL[d * 37 + jb];
#pragma unroll
            for (int jj = 0; jj < 8; jj++) {
                zacc += recvS[e][jj] * wz[jj];
                pacc += recvH[e][jj] * wh[jj];
            }
        }
        float zz = 1.f / (1.f + __expf(-zacc));
        float cl = fminf(fmaxf(pacc, -20.f), 20.f);
        float e2 = __expf(2.f * cl);
        float th = (e2 - 1.f) / (e2 + 1.f);
        tb[wv][mw * 33 + d] = ((1.f - zz) * sumh[dd] + zz * th) * msk_m;
    }
    __syncthreads();
    float* ho = h_out + (size_t)ti * NM * 32 + ((size_t)blockIdx.x * 64 + wv * 16) * 32;
#pragma unroll
    for (int i = 0; i < 8; i++) {
        int idx = i * 64 + l;
        int mm = idx >> 5, d = idx & 31;
        ho[idx] = tb[wv][mm * 33 + d];
    }
}

// ---------------- outs = relu([x, nei] @ Wo^T + b) * node_mask, scattered into qkv ----------------
// grid (NA/64, TCH); block 256 = 64 atoms x 4 d-quarters
__global__ __launch_bounds__(256) void k_outs(
    const float* __restrict__ xT, const float* __restrict__ h,
    const int* __restrict__ agraph, const void* __restrict__ Wo_w, const void* __restrict__ Wo_b,
    int t0, float* __restrict__ qkv, const int* __restrict__ flag)
{
    int bf = *flag;
    const int ti = blockIdx.y, t = t0 + ti;
    const int hh = t / 3, s2 = t - 3 * hh;
    __shared__ float WL[32 * 297];
    __shared__ float tb[4][16 * 33];
    for (int i = threadIdx.x; i < 32 * 297; i += 256) {
        int d = i / 297, k = i - d * 297;
        WL[i] = (k < 288) ? ldw(Wo_w, ((size_t)t * 32 + d) * 288 + k, bf) : 0.f;
    }
    __syncthreads();
    const int q = threadIdx.x & 3, al = threadIdx.x >> 2;
    const int a = blockIdx.x * 64 + al;
    const int d0 = q * 8;
    float nei[32];
#pragma unroll
    for (int j = 0; j < 32; j++) nei[j] = 0.f;
#pragma unroll
    for (int nb = 0; nb < 6; nb++) {
        int ag = agraph[a * 6 + nb];
        ag = min(max(ag, 0), NM - 1);
        const float* hr = h + ((size_t)ti * NM + ag) * 32;
#pragma unroll
        for (int j4 = 0; j4 < 32; j4 += 4) {
            float4 v = *(const float4*)&hr[j4];
            nei[j4] += v.x; nei[j4 + 1] += v.y; nei[j4 + 2] += v.z; nei[j4 + 3] += v.w;
        }
    }
    float acc[8];
#pragma unroll
    for (int dd = 0; dd < 8; dd++) acc[dd] = ldw(Wo_b, t * 32 + d0 + dd, bf);
    for (int kc = 0; kc < 8; kc++) {
        float xv[32];
#pragma unroll
        for (int kk = 0; kk < 32; kk++) xv[kk] = xT[(size_t)(kc * 32 + kk) * NA + a];
#pragma unroll
        for (int dd = 0; dd < 8; dd++) {
            const float* w = &WL[(d0 + dd) * 297 + kc * 32];
#pragma unroll
            for (int kk = 0; kk < 32; kk++) acc[dd] += xv[kk] * w[kk];
        }
    }
    const int wv = threadIdx.x >> 6, l = threadIdx.x & 63, aw = al & 15;
#pragma unroll
    for (int dd = 0; dd < 8; dd++) {
        const float* w = &WL[(d0 + dd) * 297 + 256];
        float s = acc[dd];
#pragma unroll
        for (int j = 0; j < 32; j++) s += nei[j] * w[j];
        s = fmaxf(s, 0.f);
        if (a == 0) s = 0.f;
        tb[wv][aw * 33 + d0 + dd] = s;
    }
    __syncthreads();
    int abase = blockIdx.x * 64 + wv * 16;
#pragma unroll
    for (int i = 0; i < 8; i++) {
        int idx = i * 64 + l;
        int mm = idx >> 5, d = idx & 31;
        float v = tb[wv][mm * 33 + d];
        size_t dst;
        if (s2 == 0) dst = (size_t)(abase + mm) * 256 + hh * 32 + d;
        else dst = (size_t)s2 * 1048576 + (size_t)hh * 131072 + (size_t)(abase + mm) * 32 + d;
        qkv[dst] = v;
    }
}

// ---------------- per-molecule 32x32 attention block ----------------
// grid (nmol, 4); block 64 (one wave, 2 heads)
__global__ __launch_bounds__(64) void k_attn_mol(
    const float* __restrict__ Qp, const float* __restrict__ Kp, const float* __restrict__ Vp,
    const int* __restrict__ scopes, float* __restrict__ ctx)
{
    int mol = blockIdx.x;
    int g = threadIdx.x >> 5;
    int head = blockIdx.y * 2 + g;
    int lane = threadIdx.x & 31;
    int start = scopes[2 * mol];
    int len = min(scopes[2 * mol + 1], 32);
    if (len <= 0) return;
    __shared__ float Ql[2][32 * 36], Kl[2][32 * 36], Vl[2][32 * 36], Pl[2][32 * 36];
    for (int i = 0; i < len; i++) {
        if (start + i >= NA) break;
        size_t base = (size_t)(start + i) * 256 + head * 32 + lane;
        Ql[g][i * 36 + lane] = Qp[base];
        Kl[g][i * 36 + lane] = Kp[base];
        Vl[g][i * 36 + lane] = Vp[base];
    }
    for (int i = len; i < 32; i++) { Vl[g][i * 36 + lane] = 0.f; Kl[g][i * 36 + lane] = 0.f; }
    float kreg[32];
#pragma unroll
    for (int d2 = 0; d2 < 32; d2++) kreg[d2] = Kl[g][lane * 36 + d2];
    const float scale = 0.17677669529663687f;   // 1/sqrt(32)
    for (int i = 0; i < len; i++) {
        float s = 0.f;
#pragma unroll
        for (int d2 = 0; d2 < 32; d2++) s += Ql[g][i * 36 + d2] * kreg[d2];
        s *= scale;
        if (lane >= len) s = -1e30f;
        float mx = s;
#pragma unroll
        for (int off = 16; off > 0; off >>= 1) mx = fmaxf(mx, __shfl_xor(mx, off, 32));
        float p = __expf(s - mx);
        if (lane >= len) p = 0.f;
        float sum = p;
#pragma unroll
        for (int off = 16; off > 0; off >>= 1) sum += __shfl_xor(sum, off, 32);
        Pl[g][i * 36 + lane] = p / sum;
    }
    for (int i = 0; i < len; i++) {
        if (start + i >= NA) break;
        float acc = 0.f;
#pragma unroll
        for (int j = 0; j < 32; j++) acc += Pl[g][i * 36 + j] * Vl[g][j * 36 + lane];
        ctx[(size_t)(start + i) * 256 + head * 32 + lane] = acc;
    }
}

// ---------------- degenerate attention rows: atom 0 -> V[0]; uncovered atoms -> mean(V) ----------------
__global__ __launch_bounds__(256) void k_attn_uniform(
    const float* __restrict__ Vp, const int* __restrict__ molid, float* __restrict__ ctx)
{
    int head = blockIdx.x;
    int s = threadIdx.x >> 5, d = threadIdx.x & 31;
    float part = 0.f;
    for (int a = s; a < NA; a += 8) part += Vp[(size_t)a * 256 + head * 32 + d];
    __shared__ float red[8 * 33];
    __shared__ float mv[32];
    red[s * 33 + d] = part;
    __syncthreads();
    if (threadIdx.x < 32) {
        float tot = 0.f;
#pragma unroll
        for (int ss = 0; ss < 8; ss++) tot += red[ss * 33 + threadIdx.x];
        mv[threadIdx.x] = tot * (1.f / 4096.f);
    }
    __syncthreads();
    float meanv = mv[d];
    float v0 = Vp[head * 32 + d];
    for (int a = s; a < NA; a += 8) {
        if (molid[a] < 0) ctx[(size_t)a * 256 + head * 32 + d] = (a == 0) ? v0 : meanv;
    }
}

// ---------------- layernorm -> out (bf16 or f32 per flag) ----------------
__global__ __launch_bounds__(256) void k_ln(
    const float* __restrict__ xo, const void* __restrict__ g_, const void* __restrict__ b_,
    void* __restrict__ out, const int* __restrict__ flag)
{
    int bf = *flag;
    int a = blockIdx.x, c = threadIdx.x;
    float v = xo[(size_t)a * 256 + c];
    __shared__ float red[4], red2[4];
    float s = v;
#pragma unroll
    for (int off = 32; off > 0; off >>= 1) s += __shfl_down(s, off);
    int w = threadIdx.x >> 6, ln2 = threadIdx.x & 63;
    if (ln2 == 0) red[w] = s;
    __syncthreads();
    float mu = (red[0] + red[1] + red[2] + red[3]) * (1.f / 256.f);
    float dv = v - mu;
    float sq = dv * dv;
#pragma unroll
    for (int off = 32; off > 0; off >>= 1) sq += __shfl_down(sq, off);
    if (ln2 == 0) red2[w] = sq;
    __syncthreads();
    float var = (red2[0] + red2[1] + red2[2] + red2[3]) * (1.f / 256.f);
    float y = dv * rsqrtf(var + 1e-5f) * ldw(g_, c, bf) + ldw(b_, c, bf);
    size_t idx = (size_t)a * 256 + c;
    if (bf) ((bf16*)out)[idx] = f2b(y);
    else    ((float*)out)[idx] = y;
}

extern "C" void kernel_launch(void* const* d_in, const int* in_sizes, int n_in,
                              void* d_out, int out_size, void* d_ws, size_t ws_size,
                              hipStream_t stream)
{
    const void* fnode  = d_in[0];
    const void* fmess  = d_in[1];
    const int*  agraph = (const int*)d_in[2];
    const int*  bgraph = (const int*)d_in[3];
    const int*  scopes = (const int*)d_in[4];
    const void* W_i_w  = d_in[5];
    const void* Wz_w   = d_in[6];
    const void* Wz_b   = d_in[7];
    const void* Wr_w   = d_in[8];
    const void* Ur_w   = d_in[9];
    const void* Ur_b   = d_in[10];
    const void* Wh_w   = d_in[11];
    const void* Wh_b   = d_in[12];
    const void* Wo_w   = d_in[13];
    const void* Wo_b   = d_in[14];
    const void* attn_w = d_in[15];
    const void* attn_b = d_in[16];
    const void* aow    = d_in[17];
    const void* bww    = d_in[18];
    const void* ln_g   = d_in[19];
    const void* ln_b   = d_in[20];
    int nmol = in_sizes[4] / 2;

    // -------- workspace layout (floats), ~56.6 MB (unchanged from passing round) --------
    const size_t CS = (size_t)TCH * 32 * NM;     // 1,048,576 floats per state array (TCH=2)
    float* p   = (float*)d_ws;
    float* xT  = p;                    p += 1048576;
    float* hmT = p;                    p += (size_t)288 * NM;       // 4,718,592
    float* cs  = p;                    p += 5 * CS;                 // 5,242,880
    float* qkv = p;                    p += 3 * 1048576;            // 3,145,728
    int*   molid = (int*)p;            p += NA;
    int*   dflag = (int*)p;            p += 1;

    float* r1 = cs;
    float* az = cs + CS;
    float* ah = cs + 2 * CS;
    float* h0 = cs + 3 * CS;
    float* h1 = cs + 4 * CS;
    // phase-A temporaries nested inside qkv (dead before qkv is written):
    float* fnode_f = qkv;              // 401,408
    float* x       = qkv + 524288;     // 1,048,576
    // post-loop aliases:
    float* Qp  = cs;                   // 1,048,576 each
    float* Kp  = cs + 1048576;
    float* Vp  = cs + 2097152;
    float* ctx = hmT;
    float* y1  = hmT + 1048576;
    float* xo  = hmT + 2097152;

    k_flag<<<1, 64, 0, stream>>>(fnode, dflag);
    k_cast<<<(401408 + 255) / 256, 256, 0, stream>>>(fnode, fnode_f, 401408, dflag);
    k_gemm_nt<<<256, 256, 0, stream>>>(fnode_f, W_i_w, 0, nullptr, 0, 0, x, 98, dflag);
    k_xpose<<<dim3(128, 8), 256, 0, stream>>>(x, xT);
    k_hmess<<<(288 * NM) / 256, 256, 0, stream>>>(x, fmess, hmT, dflag);
    k_molmap<<<(NA + 255) / 256, 256, 0, stream>>>(scopes, nmol, molid);

    for (int tc = 0; tc < 24 / TCH; tc++) {
        int t0 = tc * TCH;
        k_pre<<<dim3(NM / 512, TCH, 4), 256, 0, stream>>>(
            hmT, Wr_w, Wz_w, Wh_w, Ur_b, Wz_b, Wh_b, t0, r1, az, ah, dflag);
        k_step0<<<dim3(NM / 64, TCH), 256, 0, stream>>>(az, ah, h1);
        k_step<<<dim3(NM / 64, TCH), 256, 0, stream>>>(h1, h0, r1, az, ah, bgraph, Ur_w, Wz_w, Wh_w, t0, dflag);
        k_step<<<dim3(NM / 64, TCH), 256, 0, stream>>>(h0, h1, r1, az, ah, bgraph, Ur_w, Wz_w, Wh_w, t0, dflag);
        k_outs<<<dim3(NA / 64, TCH), 256, 0, stream>>>(xT, h1, agraph, Wo_w, Wo_b, t0, qkv, dflag);
    }

    // projections (qkv planes already in queries/keys/values layout); offsets in ELEMENTS
    k_gemm_nt<<<256, 256, 0, stream>>>(qkv,           attn_w, 0,      attn_b, 0,   1, Qp, 256, dflag);
    k_gemm_nt<<<256, 256, 0, stream>>>(qkv + 1048576, attn_w, 65536,  attn_b, 256, 1, Kp, 256, dflag);
    k_gemm_nt<<<256, 256, 0, stream>>>(qkv + 2097152, attn_w, 131072, attn_b, 512, 1, Vp, 256, dflag);

    k_attn_mol<<<dim3(nmol, 4), 64, 0, stream>>>(Qp, Kp, Vp, scopes, ctx);
    k_attn_uniform<<<8, 256, 0, stream>>>(Vp, molid, ctx);

    k_gemm_nt<<<256, 256, 0, stream>>>(ctx, aow, 0, nullptr, 0, 0, y1, 256, dflag);
    k_gemm_nt<<<256, 256, 0, stream>>>(y1,  bww, 0, nullptr, 0, 0, xo, 256, dflag);
    k_ln<<<NA, 256, 0, stream>>>(xo, ln_g, ln_b, d_out, dflag);
    (void)ws_size; (void)out_size; (void)n_in;
}